// Round 1
// baseline (601.747 us; speedup 1.0000x reference)
//
#include <hip/hip_runtime.h>

#define NEG_SLOPE 0.2f
#define EPSF 1e-16f

// ---------------- GEMM1: xh1 = x @ W1   (N x 128) @ (128 x 128) ----------------
__global__ __launch_bounds__(256) void k_gemm1(const float* __restrict__ x,
                                               const float* __restrict__ W,
                                               float* __restrict__ xh, int N) {
    __shared__ float xs[32][132];   // 32 rows x 128, padded stride 132
    __shared__ float wsh[32][128];  // one 32-row k-panel of W
    const int t = threadIdx.x;
    const int row0 = blockIdx.x * 32;

    // stage x tile (32 x 128) as float4
    for (int i = t; i < 32 * 32; i += 256) {
        int r = i >> 5, c4 = i & 31;
        float4 v = make_float4(0.f, 0.f, 0.f, 0.f);
        if (row0 + r < N) v = ((const float4*)(x + (size_t)(row0 + r) * 128))[c4];
        *(float4*)&xs[r][c4 * 4] = v;
    }

    const int r0 = (t >> 5) * 4;   // 8 row-groups of 4
    const int c0 = (t & 31) * 4;   // 32 col-groups of 4
    float acc[4][4] = {};

    for (int kp = 0; kp < 128; kp += 32) {
        __syncthreads();           // x tile ready / previous panel consumed
        for (int i = t; i < 32 * 32; i += 256) {
            int kr = i >> 5, c4 = i & 31;
            ((float4*)&wsh[kr][0])[c4] =
                ((const float4*)(W + (size_t)(kp + kr) * 128))[c4];
        }
        __syncthreads();
        #pragma unroll
        for (int kk = 0; kk < 32; ++kk) {
            const float4 wv = *(const float4*)&wsh[kk][c0];
            const int k = kp + kk;
            #pragma unroll
            for (int i = 0; i < 4; ++i) {
                const float xv = xs[r0 + i][k];
                acc[i][0] += xv * wv.x;
                acc[i][1] += xv * wv.y;
                acc[i][2] += xv * wv.z;
                acc[i][3] += xv * wv.w;
            }
        }
    }
    #pragma unroll
    for (int i = 0; i < 4; ++i) {
        const int row = row0 + r0 + i;
        if (row < N) {
            *(float4*)(xh + (size_t)row * 128 + c0) =
                make_float4(acc[i][0], acc[i][1], acc[i][2], acc[i][3]);
        }
    }
}

// ------------- e_src1/e_dst1: per (node, head) dot with att vectors -------------
__global__ __launch_bounds__(256) void k_esed1(const float* __restrict__ xh,
                                               const float* __restrict__ asrc,
                                               const float* __restrict__ adst,
                                               float* __restrict__ es,
                                               float* __restrict__ ed, int N) {
    int i = blockIdx.x * 256 + threadIdx.x;   // i = n*8 + h
    if (i >= N * 8) return;
    const int h = i & 7;
    const float4* xp = (const float4*)(xh + (size_t)i * 16);
    const float4* ap = (const float4*)(asrc + h * 16);
    const float4* bp = (const float4*)(adst + h * 16);
    float s = 0.f, d = 0.f;
    #pragma unroll
    for (int c = 0; c < 4; ++c) {
        float4 v = xp[c], a = ap[c], b = bp[c];
        s += v.x * a.x + v.y * a.y + v.z * a.z + v.w * a.w;
        d += v.x * b.x + v.y * b.y + v.z * b.z + v.w * b.w;
    }
    es[i] = s; ed[i] = d;
}

// ------------------------- CSR build: histogram by dst -------------------------
__global__ void k_hist(const int* __restrict__ ei, int E, int N, int* __restrict__ deg) {
    const int Et = E + N;
    for (int e = blockIdx.x * blockDim.x + threadIdx.x; e < Et;
         e += gridDim.x * blockDim.x) {
        int d = (e < E) ? ei[E + e] : (e - E);   // self-loop tail
        atomicAdd(&deg[d], 1);
    }
}

__global__ __launch_bounds__(256) void k_scan_a(const int* __restrict__ deg,
                                                int* __restrict__ rowp,
                                                int* __restrict__ bsum, int N) {
    __shared__ int sd[256];
    const int t = threadIdx.x;
    const int i = blockIdx.x * 256 + t;
    const int v = (i < N) ? deg[i] : 0;
    sd[t] = v;
    __syncthreads();
    for (int off = 1; off < 256; off <<= 1) {
        int add = (t >= off) ? sd[t - off] : 0;
        __syncthreads();
        sd[t] += add;
        __syncthreads();
    }
    if (i < N) rowp[i] = sd[t] - v;              // exclusive within block
    if (t == 255) bsum[blockIdx.x] = sd[255];
}

__global__ __launch_bounds__(512) void k_scan_b(int* __restrict__ bsum, int NB) {
    __shared__ int sd[512];
    const int t = threadIdx.x;
    const int v = (t < NB) ? bsum[t] : 0;
    sd[t] = v;
    __syncthreads();
    for (int off = 1; off < 512; off <<= 1) {
        int add = (t >= off) ? sd[t - off] : 0;
        __syncthreads();
        sd[t] += add;
        __syncthreads();
    }
    if (t < NB) bsum[t] = sd[t] - v;             // exclusive block bases
}

__global__ __launch_bounds__(256) void k_scan_c(int* __restrict__ rowp,
                                                const int* __restrict__ bsum,
                                                int* __restrict__ fill, int N) {
    const int i = blockIdx.x * 256 + threadIdx.x;
    if (i >= N) return;
    const int v = rowp[i] + bsum[blockIdx.x];
    rowp[i] = v;
    fill[i] = v;
}

__global__ void k_scatter(const int* __restrict__ ei, int E, int N,
                          int* __restrict__ fill, int* __restrict__ csr) {
    const int Et = E + N;
    for (int e = blockIdx.x * blockDim.x + threadIdx.x; e < Et;
         e += gridDim.x * blockDim.x) {
        int s, d;
        if (e < E) { s = ei[e]; d = ei[E + e]; }
        else       { s = e - E; d = e - E; }
        const int pos = atomicAdd(&fill[d], 1);
        csr[pos] = s;
    }
}

// -------- layer-1 aggregate: one wave per dst node, 2 channels per lane --------
__global__ __launch_bounds__(256) void k_l1(const float* __restrict__ xh,
                                            const float* __restrict__ es,
                                            const float* __restrict__ ed,
                                            const int* __restrict__ rowp,
                                            const int* __restrict__ deg,
                                            const int* __restrict__ csr,
                                            const float* __restrict__ b1,
                                            float* __restrict__ hout, int N) {
    const int wave = threadIdx.x >> 6;
    const int lane = threadIdx.x & 63;
    const int n = blockIdx.x * 4 + wave;
    if (n >= N) return;
    const int h = lane >> 3;                     // channels 2*lane, 2*lane+1 -> head
    const float edv = ed[n * 8 + h];
    const int start = rowp[n];
    const int cnt = deg[n];
    float acc0 = 0.f, acc1 = 0.f, dsum = 0.f;
    int snext = (cnt > 0) ? csr[start] : 0;
    for (int k = 0; k < cnt; ++k) {
        const int s = snext;
        if (k + 1 < cnt) snext = csr[start + k + 1];
        float a = es[s * 8 + h] + edv;
        a = (a > 0.f) ? a : NEG_SLOPE * a;
        const float ea = __expf(a);
        const float2 v = *(const float2*)(xh + (size_t)s * 128 + lane * 2);
        acc0 += ea * v.x;
        acc1 += ea * v.y;
        dsum += ea;
    }
    const float inv = 1.f / (dsum + EPSF);
    float o0 = acc0 * inv + b1[lane * 2];
    float o1 = acc1 * inv + b1[lane * 2 + 1];
    o0 = (o0 > 0.f) ? o0 : expm1f(o0);           // ELU
    o1 = (o1 > 0.f) ? o1 : expm1f(o1);
    *(float2*)(hout + (size_t)n * 128 + lane * 2) = make_float2(o0, o1);
}

// ---------------- GEMM2: xh2 = h @ W2   (N x 128) @ (128 x 40) -----------------
__global__ __launch_bounds__(256) void k_gemm2(const float* __restrict__ h,
                                               const float* __restrict__ W2,
                                               float* __restrict__ xh2, int N) {
    __shared__ float w[128 * 40];
    for (int i = threadIdx.x; i < 128 * 40 / 4; i += 256)
        ((float4*)w)[i] = ((const float4*)W2)[i];
    __syncthreads();
    const int n = blockIdx.x * 256 + threadIdx.x;
    if (n >= N) return;
    float acc[40];
    #pragma unroll
    for (int j = 0; j < 40; ++j) acc[j] = 0.f;
    const float4* hr = (const float4*)(h + (size_t)n * 128);
    for (int k4 = 0; k4 < 32; ++k4) {
        const float4 hv = hr[k4];
        const float hx[4] = {hv.x, hv.y, hv.z, hv.w};
        #pragma unroll
        for (int kk = 0; kk < 4; ++kk) {
            const float* wr = &w[(k4 * 4 + kk) * 40];
            #pragma unroll
            for (int j = 0; j < 40; j += 4) {
                const float4 wv = *(const float4*)&wr[j];
                acc[j]     += hx[kk] * wv.x;
                acc[j + 1] += hx[kk] * wv.y;
                acc[j + 2] += hx[kk] * wv.z;
                acc[j + 3] += hx[kk] * wv.w;
            }
        }
    }
    float4* op = (float4*)(xh2 + (size_t)n * 40);
    #pragma unroll
    for (int j = 0; j < 10; ++j)
        op[j] = make_float4(acc[4 * j], acc[4 * j + 1], acc[4 * j + 2], acc[4 * j + 3]);
}

// ---------------- e_src2/e_dst2: wave per node, shuffle reduce ------------------
__global__ __launch_bounds__(256) void k_esed2(const float* __restrict__ xh2,
                                               const float* __restrict__ as2,
                                               const float* __restrict__ ad2,
                                               float* __restrict__ es2,
                                               float* __restrict__ ed2, int N) {
    const int wave = threadIdx.x >> 6;
    const int lane = threadIdx.x & 63;
    const int n = blockIdx.x * 4 + wave;
    if (n >= N) return;
    float v = 0.f, a = 0.f, b = 0.f;
    if (lane < 40) {
        v = xh2[(size_t)n * 40 + lane];
        a = as2[lane];
        b = ad2[lane];
    }
    float s = v * a, d = v * b;
    #pragma unroll
    for (int off = 32; off >= 1; off >>= 1) {
        s += __shfl_xor(s, off, 64);
        d += __shfl_xor(d, off, 64);
    }
    if (lane == 0) { es2[n] = s; ed2[n] = d; }
}

// -------- layer-2 aggregate: one wave per dst node, lane = class channel --------
__global__ __launch_bounds__(256) void k_l2(const float* __restrict__ xh2,
                                            const float* __restrict__ es2,
                                            const float* __restrict__ ed2,
                                            const int* __restrict__ rowp,
                                            const int* __restrict__ deg,
                                            const int* __restrict__ csr,
                                            const float* __restrict__ b2,
                                            float* __restrict__ out, int N) {
    const int wave = threadIdx.x >> 6;
    const int lane = threadIdx.x & 63;
    const int n = blockIdx.x * 4 + wave;
    if (n >= N) return;
    const float edv = ed2[n];
    const int start = rowp[n];
    const int cnt = deg[n];
    float acc = 0.f, dsum = 0.f;
    int snext = (cnt > 0) ? csr[start] : 0;
    for (int k = 0; k < cnt; ++k) {
        const int s = snext;
        if (k + 1 < cnt) snext = csr[start + k + 1];
        float a = es2[s] + edv;
        a = (a > 0.f) ? a : NEG_SLOPE * a;
        const float ea = __expf(a);
        const float v = (lane < 40) ? xh2[(size_t)s * 40 + lane] : 0.f;
        acc += ea * v;
        dsum += ea;
    }
    if (lane < 40)
        out[(size_t)n * 40 + lane] = acc / (dsum + EPSF) + b2[lane];
}

extern "C" void kernel_launch(void* const* d_in, const int* in_sizes, int n_in,
                              void* d_out, int out_size, void* d_ws, size_t ws_size,
                              hipStream_t stream) {
    const float* x   = (const float*)d_in[0];
    const int*   ei  = (const int*)d_in[1];
    const float* W1  = (const float*)d_in[2];
    const float* as1 = (const float*)d_in[3];
    const float* ad1 = (const float*)d_in[4];
    const float* b1  = (const float*)d_in[5];
    const float* W2  = (const float*)d_in[6];
    const float* as2 = (const float*)d_in[7];
    const float* ad2 = (const float*)d_in[8];
    const float* b2  = (const float*)d_in[9];
    float* out = (float*)d_out;

    const int N  = in_sizes[0] / 128;
    const int E  = in_sizes[1] / 2;
    const int Et = E + N;
    const int NB = (N + 255) / 256;   // 391 for N=100000 (fits the 512-wide scan_b)

    // ---- workspace layout (~117 MB) ----
    char* p = (char*)d_ws;
    float* xh1  = (float*)p; p += (size_t)N * 128 * 4;
    float* es1  = (float*)p; p += (size_t)N * 8 * 4;
    float* ed1  = (float*)p; p += (size_t)N * 8 * 4;
    int*   deg  = (int*)p;   p += (size_t)N * 4;
    int*   rowp = (int*)p;   p += (size_t)N * 4;
    int*   fill = (int*)p;   p += (size_t)N * 4;
    int*   bsum = (int*)p;   p += 2048 * 4;
    int*   csr  = (int*)p;   p += (size_t)Et * 4;
    float* hbuf = (float*)p; p += (size_t)N * 128 * 4;
    // aliases: dead after k_l1
    float* xh2 = xh1;
    float* es2 = es1;
    float* ed2 = ed1;

    hipMemsetAsync(deg, 0, (size_t)N * 4, stream);

    k_gemm1 <<<(N + 31) / 32,      256, 0, stream>>>(x, W1, xh1, N);
    k_esed1 <<<(N * 8 + 255)/256,  256, 0, stream>>>(xh1, as1, ad1, es1, ed1, N);
    k_hist  <<<2048,               256, 0, stream>>>(ei, E, N, deg);
    k_scan_a<<<NB,                 256, 0, stream>>>(deg, rowp, bsum, N);
    k_scan_b<<<1,                  512, 0, stream>>>(bsum, NB);
    k_scan_c<<<NB,                 256, 0, stream>>>(rowp, bsum, fill, N);
    k_scatter<<<2048,              256, 0, stream>>>(ei, E, N, fill, csr);
    k_l1    <<<(N + 3) / 4,        256, 0, stream>>>(xh1, es1, ed1, rowp, deg, csr, b1, hbuf, N);
    k_gemm2 <<<(N + 255) / 256,    256, 0, stream>>>(hbuf, W2, xh2, N);
    k_esed2 <<<(N + 3) / 4,        256, 0, stream>>>(xh2, as2, ad2, es2, ed2, N);
    k_l2    <<<(N + 3) / 4,        256, 0, stream>>>(xh2, es2, ed2, rowp, deg, csr, b2, out, N);
}